// Round 4
// baseline (241.604 us; speedup 1.0000x reference)
//
#include <hip/hip_runtime.h>
#include <stdint.h>

// DETR PartMap: [2, B, Q, H, W] outside-box masks (1.0 outside, 0.0 inside).
// B=64, Q=300, H=W=40. Output 61.44M fp32 = 245.8 MB -> pure write-BW problem.
//
// R4: fill-mimicking streamer. Phase 1 computes each (s,b,q) box ONCE into a
// 38,400-entry x 8B table in d_ws (40-bit x-outside mask + y1/y2 bytes).
// Phase 2 launches EXACTLY 8192 waves (2048 blocks x 256 = 32 waves/CU, one
// full residency, no multi-round tail), grid-striding over 64-float4 chunks
// (240,000 chunks, 29-30 per wave, never partial). Per float4: one 8B
// L1-broadcast table load + ~24 VALU + one coalesced dwordx4 store.
// R1-R3 showed inst count is NOT the limiter (15 vs 40 insts/f4 -> same time);
// this round attacks wave structure: prologue amortization + zero tail.

#define B_     64
#define Q_     300
#define HM     40
#define WM     40
#define NBOX   38400              // 2*B*Q
#define TOTAL4 15360000           // 2*B*Q*H*W / 4
#define NCHUNK 240000             // TOTAL4 / 64
#define NWAVE  8192               // 2048 blocks * 4 waves
#define KFULL  29                 // chunks per wave (all waves)
// extra chunk for wid < NCHUNK - KFULL*NWAVE = 2432

__global__ __launch_bounds__(256) void box_prep_kernel(
    const float* __restrict__ obj,
    const float* __restrict__ sub,
    const int*   __restrict__ img,     // [B,2] = (h, w) int32
    uint32_t*    __restrict__ tbl)     // [NBOX][2]: {xmask_lo, xmask_hi|y1<<8|y2<<16}
{
    #pragma clang fp contract(off)
    int id = blockIdx.x * 256 + threadIdx.x;
    if (id >= NBOX) return;

    // id = (s*64 + b)*300 + q
    int q  = id % Q_;
    int sb = id / Q_;
    int b  = sb & 63;
    int s  = sb >> 6;

    const float* coord = s ? sub : obj;
    float4 c = ((const float4*)coord)[b * Q_ + q];   // (cx, cy, w, h)

    float shh = (float)img[b * 2 + 0];
    float sww = (float)img[b * 2 + 1];

    // Exact numpy op order: (cx - 0.5*w) * size / 32, floor, cast. No FMA.
    float x1f = (c.x - 0.5f * c.z) * sww / 32.0f;
    float y1f = (c.y - 0.5f * c.w) * shh / 32.0f;
    float x2f = (c.x + 0.5f * c.z) * sww / 32.0f;
    float y2f = (c.y + 0.5f * c.w) * shh / 32.0f;

    int x1 = (int)floorf(x1f);                 // >= -20, <= large
    int y1 = (int)floorf(y1f);
    int x2 = min((int)floorf(x2f), WM - 1);    // in [.,39]
    int y2 = min((int)floorf(y2f), HM - 1);

    // 40-bit x-outside mask: bit x set iff (x < x1 || x > x2)
    uint64_t blo = (x1 <= 0) ? ~0ull : ~((1ull << x1) - 1ull);
    uint64_t bhi = (x2 < 0) ? 0ull : ((1ull << (x2 + 1)) - 1ull);
    uint64_t outside = (~(blo & bhi)) & ((1ull << 40) - 1ull);

    uint32_t d0 = (uint32_t)outside;
    uint32_t d1 = ((uint32_t)(outside >> 32) & 0xFFu)
                | (((uint32_t)y1 & 0xFFu) << 8)
                | (((uint32_t)y2 & 0xFFu) << 16);

    tbl[id * 2 + 0] = d0;
    tbl[id * 2 + 1] = d1;
}

__device__ __forceinline__ void emit_chunk(
    int c, int lane, const uint64_t* __restrict__ tbl, float4* __restrict__ out)
{
    int p = (c << 6) | lane;             // float4 index < TOTAL4

    int e   = (int)((unsigned)p / 400u); // entry id (compiler magic-mul)
    int rem = p - e * 400;               // position within entry, < 400
    int h   = (int)((unsigned)rem / 10u);
    int w4  = rem - h * 10;
    int sh  = w4 * 4;

    uint64_t t = tbl[e];                 // 8B dwordx2, L1 broadcast (64 lanes
                                         // touch at most 2 entries)
    int y1 = (int)(int8_t)(t >> 40);
    int y2 = (int)(int8_t)(t >> 48);

    // all-ones if row h outside [y1,y2]
    int rneg = ((h - y1) | (y2 - h)) >> 31;

    // bits sh..sh+3 of the 40-bit x-outside mask (sh<=36, so y1/y2 bytes at
    // bits >=40 never reach bits 0..3)
    uint32_t m = (uint32_t)(t >> sh) | (uint32_t)rneg;

    float4 r;
    r.x = (float)( m        & 1u);
    r.y = (float)((m >> 1u) & 1u);
    r.z = (float)((m >> 2u) & 1u);
    r.w = (float)((m >> 3u) & 1u);

    out[p] = r;
}

__global__ __launch_bounds__(256) void partmap_stream(
    const uint64_t* __restrict__ tbl,
    float4*         __restrict__ out)
{
    const int lane = threadIdx.x & 63;
    const int wid  = (blockIdx.x << 2) | (threadIdx.x >> 6);   // 0..8191

    int c = wid;
    #pragma unroll 4
    for (int k = 0; k < KFULL; ++k) {
        emit_chunk(c, lane, tbl, out);
        c += NWAVE;
    }
    if (wid < NCHUNK - KFULL * NWAVE)    // 2432 waves do a 30th chunk
        emit_chunk(c, lane, tbl, out);
}

extern "C" void kernel_launch(void* const* d_in, const int* in_sizes, int n_in,
                              void* d_out, int out_size, void* d_ws, size_t ws_size,
                              hipStream_t stream) {
    const float* obj = (const float*)d_in[0];   // [B,Q,4] f32
    const float* sub = (const float*)d_in[1];   // [B,Q,4] f32
    const int*   img = (const int*)d_in[2];     // [B,2] int32 (h, w)
    // d_in[3] = mask (bool) — only its shape is used; ignored.

    uint32_t* tbl = (uint32_t*)d_ws;            // 38,400 * 8 B = 307 KB
    float4*   out = (float4*)d_out;

    box_prep_kernel<<<dim3((NBOX + 255) / 256), dim3(256), 0, stream>>>(
        obj, sub, img, tbl);
    partmap_stream<<<dim3(2048), dim3(256), 0, stream>>>(
        (const uint64_t*)tbl, out);
}